// Round 12
// baseline (399.185 us; speedup 1.0000x reference)
//
#include <hip/hip_runtime.h>
#include <math.h>

#define D_FEAT 128
#define SCAN_ITEMS 2048   // items per scan block (256 thr * 8)
#define NHB 256           // hist blocks (private LDS histograms) — 1 per CU
#define HTHREADS 1024     // hist block size: 16 waves/CU to hide LDS-atomic latency
#define MAXPAIR 25600     // max (M+1)/2 supported by static LDS (100 KB)

typedef float f32x4 __attribute__((ext_vector_type(4)));
typedef short short8 __attribute__((ext_vector_type(8)));

// float -> bf16 (RNE), on raw bits
__device__ __forceinline__ unsigned short f2bf(float f) {
    unsigned int u = __float_as_uint(f);
    u += 0x7FFFu + ((u >> 16) & 1u);
    return (unsigned short)(u >> 16);
}

// setup: off[M] = n_edges + fragment-major bf16 W:
// Wfrag[((c*8+s)*64+l)*8+i] = bf16( W[col=c*16+(l&15)][k=s*32+((l>>4)<<3)+i] )
__global__ __launch_bounds__(256) void setup_kernel(const float* __restrict__ W,
                                                    unsigned short* __restrict__ Wfrag,
                                                    int* __restrict__ off,
                                                    int M, int n_edges) {
    int i = blockIdx.x * 256 + threadIdx.x;
    if (i < 2 * D_FEAT * D_FEAT) {
        int ii = i & 7, lf = (i >> 3) & 63, sf = (i >> 9) & 7, cf = i >> 12;
        int col = cf * 16 + (lf & 15);
        int k   = sf * 32 + ((lf >> 4) << 3) + ii;
        Wfrag[i] = f2bf(W[(size_t)col * (2 * D_FEAT) + k]);
    }
    if (i == 0) off[M] = n_edges;
}

// 1) LDS-privatized histogram v3: 256 blocks x 1024 threads (16 waves/CU —
//    enough issue parallelism to pipeline LDS-atomic latency; r11's 4 waves/CU
//    was latency-bound at ~16cyc/lane-atomic). Bins packed 2-per-u32 as u16
//    halves; <=6250 edges/block so no overflow. ZERO global atomics.
__global__ __launch_bounds__(HTHREADS) void hist_kernel(const int* __restrict__ index,
                                                        unsigned int* __restrict__ bhist,
                                                        int npair, int n4, int n) {
    __shared__ unsigned int h[MAXPAIR];
    const int b = blockIdx.x, t = threadIdx.x;

    for (int j = t; j < npair; j += HTHREADS) h[j] = 0u;
    __syncthreads();

    const int per = (n4 + NHB - 1) / NHB;
    const int i0 = b * per;
    const int i1 = min(n4, i0 + per);
    const int4* idx4 = reinterpret_cast<const int4*>(index);
    for (int i = i0 + t; i < i1; i += HTHREADS) {
        int4 v = idx4[i];
        atomicAdd(&h[v.x >> 1], 1u << ((v.x & 1) << 4));
        atomicAdd(&h[v.y >> 1], 1u << ((v.y & 1) << 4));
        atomicAdd(&h[v.z >> 1], 1u << ((v.z & 1) << 4));
        atomicAdd(&h[v.w >> 1], 1u << ((v.w & 1) << 4));
    }
    if (b == 0) {   // scalar tail (none when n % 4 == 0)
        for (int r = 4 * n4 + t; r < n; r += HTHREADS) {
            int v = index[r];
            atomicAdd(&h[v >> 1], 1u << ((v & 1) << 4));
        }
    }
    __syncthreads();

    unsigned int* dst = bhist + (size_t)b * npair;
    for (int j = t; j < npair; j += HTHREADS) dst[j] = h[j];
}

// 1b) fold the NHB private histograms into cnt (coalesced reads, no atomics)
__global__ __launch_bounds__(256) void sumhist_kernel(const unsigned int* __restrict__ bhist,
                                                      int* __restrict__ cnt,
                                                      int npair, int M) {
    int i = blockIdx.x * 256 + threadIdx.x;
    if (i >= npair) return;
    int lo = 0, hi = 0;
    for (int b = 0; b < NHB; ++b) {
        unsigned int v = bhist[(size_t)b * npair + i];
        lo += (int)(v & 0xFFFFu);
        hi += (int)(v >> 16);
    }
    if (2 * i < M)     cnt[2 * i]     = lo;
    if (2 * i + 1 < M) cnt[2 * i + 1] = hi;
}

// 2) FUSED single-kernel exclusive scan:
//    block b coalesced-sums cnt[0 .. b*2048) for its base, then scans its chunk.
__global__ __launch_bounds__(256) void scan_kernel(const int* __restrict__ cnt,
                                                   int* __restrict__ off,
                                                   int* __restrict__ cursor, int n) {
    __shared__ int sh[SCAN_ITEMS];
    __shared__ int ts[256];
    __shared__ int pre[256];
    const int b = blockIdx.x, t = threadIdx.x;
    const int base = b * SCAN_ITEMS;

    int p = 0;
    for (int i = t; i < base; i += 256) p += cnt[i];
    pre[t] = p;
    __syncthreads();
    for (int st = 128; st > 0; st >>= 1) {
        if (t < st) pre[t] += pre[t + st];
        __syncthreads();
    }
    const int block_base = pre[0];
    __syncthreads();

    #pragma unroll
    for (int j = 0; j < 8; ++j) {
        int i = base + j * 256 + t;
        sh[j * 256 + t] = (i < n) ? cnt[i] : 0;
    }
    __syncthreads();
    int s = 0;
    #pragma unroll
    for (int j = 0; j < 8; ++j) s += sh[t * 8 + j];
    ts[t] = s;
    __syncthreads();
    for (int st = 1; st < 256; st <<= 1) {
        int u = (t >= st) ? ts[t - st] : 0;
        __syncthreads();
        ts[t] += u;
        __syncthreads();
    }
    int run = block_base + ts[t] - s;
    #pragma unroll
    for (int j = 0; j < 8; ++j) {
        int i = base + t * 8 + j;
        if (i < n) {
            off[i] = run;
            cursor[i] = run;
            run += sh[t * 8 + j];
        }
    }
}

// 3) scatter edge ids into segment-sorted order (int4 loads)
__global__ __launch_bounds__(256) void order_kernel(const int* __restrict__ index,
                                                    int* __restrict__ cursor,
                                                    int* __restrict__ order, int n4, int n) {
    int i = blockIdx.x * 256 + threadIdx.x;
    if (i < n4) {
        int4 v = reinterpret_cast<const int4*>(index)[i];
        int e = 4 * i;
        order[atomicAdd(&cursor[v.x], 1)] = e;
        order[atomicAdd(&cursor[v.y], 1)] = e + 1;
        order[atomicAdd(&cursor[v.z], 1)] = e + 2;
        order[atomicAdd(&cursor[v.w], 1)] = e + 3;
    }
    int rem = 4 * n4 + i;
    if (i < n - 4 * n4) order[atomicAdd(&cursor[index[rem]], 1)] = rem;
}

// 4) one wave per segment (round-9 form: 16B/lane, uniform trips, predicated)
__global__ __launch_bounds__(256) void reduce_kernel(
    const float* __restrict__ src, const int* __restrict__ order,
    const int* __restrict__ off, unsigned short* __restrict__ A_b, int nseg)
{
    int wid  = (blockIdx.x * 256 + threadIdx.x) >> 6;
    int lane = threadIdx.x & 63;
    if (wid >= nseg) return;
    const int half = lane >> 5;
    const int fl   = (lane & 31) << 2;

    const int start = off[wid], end = off[wid + 1];

    f32x4 s = {0.f, 0.f, 0.f, 0.f};
    f32x4 m = {-INFINITY, -INFINITY, -INFINITY, -INFINITY};

    for (int base = start; base < end; base += 64) {
        int idx = base + lane;
        int eo  = (idx < end) ? order[idx] : 0;
        int lim = end - base; if (lim > 64) lim = 64;
        #pragma unroll 2
        for (int j = 0; j < lim; j += 2) {
            int jj = j + half;
            int e  = __shfl(eo, jj);
            if (jj < lim) {
                f32x4 v = *reinterpret_cast<const f32x4*>(src + (size_t)e * D_FEAT + fl);
                s.x += v.x; s.y += v.y; s.z += v.z; s.w += v.w;
                m.x = fmaxf(m.x, v.x); m.y = fmaxf(m.y, v.y);
                m.z = fmaxf(m.z, v.z); m.w = fmaxf(m.w, v.w);
            }
        }
    }

    s.x += __shfl_xor(s.x, 32); s.y += __shfl_xor(s.y, 32);
    s.z += __shfl_xor(s.z, 32); s.w += __shfl_xor(s.w, 32);
    m.x = fmaxf(m.x, __shfl_xor(m.x, 32)); m.y = fmaxf(m.y, __shfl_xor(m.y, 32));
    m.z = fmaxf(m.z, __shfl_xor(m.z, 32)); m.w = fmaxf(m.w, __shfl_xor(m.w, 32));

    if (end == start) { m.x = 0.f; m.y = 0.f; m.z = 0.f; m.w = 0.f; }

    const f32x4 o = (half == 0) ? s : m;
    unsigned int lo = (unsigned int)f2bf(o.x) | ((unsigned int)f2bf(o.y) << 16);
    unsigned int hi = (unsigned int)f2bf(o.z) | ((unsigned int)f2bf(o.w) << 16);
    unsigned short* row = A_b + (size_t)wid * (2 * D_FEAT) + half * D_FEAT;
    uint2 pk = make_uint2(lo, hi);
    *reinterpret_cast<uint2*>(row + fl) = pk;
}

// 5) MFMA GEMM: out[M,128] = A_b[M,256](bf16) @ W^T + bias, fp32 accum.
__global__ __launch_bounds__(256) void gemm_mfma_kernel(
    const unsigned short* __restrict__ A_b, const unsigned short* __restrict__ Wfrag,
    const float* __restrict__ bias, float* __restrict__ out, int M)
{
    const int w  = threadIdx.x >> 6;
    const int l  = threadIdx.x & 63;
    const int m0 = blockIdx.x * 64 + w * 16;
    if (m0 >= M) return;

    const int arow = m0 + (l & 15);
    const int kgrp = (l >> 4) << 3;

    f32x4 acc[8];
    #pragma unroll
    for (int c = 0; c < 8; ++c) acc[c] = (f32x4){0.f, 0.f, 0.f, 0.f};

    #pragma unroll
    for (int s = 0; s < 8; ++s) {
        short8 a = *reinterpret_cast<const short8*>(A_b + (size_t)arow * 256 + s * 32 + kgrp);
        #pragma unroll
        for (int c = 0; c < 8; ++c) {
            short8 b = *reinterpret_cast<const short8*>(Wfrag + (((size_t)(c * 8 + s)) * 64 + l) * 8);
            acc[c] = __builtin_amdgcn_mfma_f32_16x16x32_bf16(a, b, acc[c], 0, 0, 0);
        }
    }

    const int r0   = m0 + ((l >> 4) << 2);
    const int colb = l & 15;
    #pragma unroll
    for (int c = 0; c < 8; ++c) {
        int col = c * 16 + colb;
        float bv = bias[col];
        #pragma unroll
        for (int r = 0; r < 4; ++r) {
            int rw = r0 + r;
            if (rw < M) out[(size_t)rw * D_FEAT + col] = acc[c][r] + bv;
        }
    }
}

extern "C" void kernel_launch(void* const* d_in, const int* in_sizes, int n_in,
                              void* d_out, int out_size, void* d_ws, size_t ws_size,
                              hipStream_t stream) {
    const float* src   = (const float*)d_in[0];
    const int*   index = (const int*)d_in[1];
    const float* W     = (const float*)d_in[2];
    const float* bias  = (const float*)d_in[3];

    const int n_edges = in_sizes[1];            // 1,600,000
    const int M       = out_size / D_FEAT;      // 50,000
    const int Mpad    = (M + 63) & ~63;
    const int npair   = (M + 1) >> 1;           // 25,000 (<= MAXPAIR)

    // workspace layout
    unsigned short* A_b   = (unsigned short*)d_ws;            // Mpad * 256 bf16
    unsigned short* Wfrag = A_b + (size_t)Mpad * 2 * D_FEAT;  // 32768 bf16
    int*   cnt    = (int*)(Wfrag + 2 * D_FEAT * D_FEAT);      // M
    int*   off    = cnt + M;                                  // M + 1
    int*   cursor = off + M + 1;                              // M
    int*   order  = cursor + M;                               // n_edges
    unsigned int* bhist = (unsigned int*)(order + n_edges);   // NHB * npair

    const int nblk = (M + SCAN_ITEMS - 1) / SCAN_ITEMS;       // 25

    setup_kernel<<<(2 * D_FEAT * D_FEAT + 255) / 256, 256, 0, stream>>>(
        W, Wfrag, off, M, n_edges);

    int n4 = n_edges / 4;
    hist_kernel<<<NHB, HTHREADS, 0, stream>>>(index, bhist, npair, n4, n_edges);
    sumhist_kernel<<<(npair + 255) / 256, 256, 0, stream>>>(bhist, cnt, npair, M);

    scan_kernel<<<nblk, 256, 0, stream>>>(cnt, off, cursor, M);

    int eb4 = (max(n4, n_edges - 4 * n4) + 255) / 256;
    order_kernel<<<eb4, 256, 0, stream>>>(index, cursor, order, n4, n_edges);

    int rb = (M * 64 + 255) / 256;
    reduce_kernel<<<rb, 256, 0, stream>>>(src, order, off, A_b, M);

    gemm_mfma_kernel<<<(M + 63) / 64, 256, 0, stream>>>(A_b, Wfrag, bias, (float*)d_out, M);
}

// Round 13
// 384.896 us; speedup vs baseline: 1.0371x; 1.0371x over previous
//
#include <hip/hip_runtime.h>
#include <math.h>

#define D_FEAT 128
#define SCAN_ITEMS 2048   // items per scan block (256 thr * 8)
#define NHB 256           // hist blocks (private LDS histograms) — 1 per CU
#define HTHREADS 1024     // hist block size
#define MAXPAIR 25600     // max (M+1)/2 supported by static LDS (100 KB)
#define REP_R 2           // DIAGNOSTIC: reduce body repeated (idempotent) so the
                          // dispatch breaches the ~490us fill ceiling -> top-5 counters.

typedef float f32x4 __attribute__((ext_vector_type(4)));
typedef short short8 __attribute__((ext_vector_type(8)));

// float -> bf16 (RNE), on raw bits
__device__ __forceinline__ unsigned short f2bf(float f) {
    unsigned int u = __float_as_uint(f);
    u += 0x7FFFu + ((u >> 16) & 1u);
    return (unsigned short)(u >> 16);
}

// 1) LDS-privatized histogram (zero global atomics). Block NHB-1 additionally
//    performs the former setup_kernel work (Wfrag build + off[M]) — one less launch.
//    Wfrag[((c*8+s)*64+l)*8+i] = bf16( W[col=c*16+(l&15)][k=s*32+((l>>4)<<3)+i] )
__global__ __launch_bounds__(HTHREADS) void hist_kernel(const int* __restrict__ index,
                                                        unsigned int* __restrict__ bhist,
                                                        const float* __restrict__ W,
                                                        unsigned short* __restrict__ Wfrag,
                                                        int* __restrict__ off,
                                                        int M, int npair, int n4, int n) {
    __shared__ unsigned int h[MAXPAIR];
    const int b = blockIdx.x, t = threadIdx.x;

    if (b == NHB - 1) {   // folded setup: fragment-major bf16 W + off[M]
        for (int i = t; i < 2 * D_FEAT * D_FEAT; i += HTHREADS) {
            int ii = i & 7, lf = (i >> 3) & 63, sf = (i >> 9) & 7, cf = i >> 12;
            int col = cf * 16 + (lf & 15);
            int k   = sf * 32 + ((lf >> 4) << 3) + ii;
            Wfrag[i] = f2bf(W[(size_t)col * (2 * D_FEAT) + k]);
        }
        if (t == 0) off[M] = n;
    }

    for (int j = t; j < npair; j += HTHREADS) h[j] = 0u;
    __syncthreads();

    const int per = (n4 + NHB - 1) / NHB;
    const int i0 = b * per;
    const int i1 = min(n4, i0 + per);
    const int4* idx4 = reinterpret_cast<const int4*>(index);
    for (int i = i0 + t; i < i1; i += HTHREADS) {
        int4 v = idx4[i];
        atomicAdd(&h[v.x >> 1], 1u << ((v.x & 1) << 4));
        atomicAdd(&h[v.y >> 1], 1u << ((v.y & 1) << 4));
        atomicAdd(&h[v.z >> 1], 1u << ((v.z & 1) << 4));
        atomicAdd(&h[v.w >> 1], 1u << ((v.w & 1) << 4));
    }
    if (b == 0) {   // scalar tail (none when n % 4 == 0)
        for (int r = 4 * n4 + t; r < n; r += HTHREADS) {
            int v = index[r];
            atomicAdd(&h[v >> 1], 1u << ((v & 1) << 4));
        }
    }
    __syncthreads();

    unsigned int* dst = bhist + (size_t)b * npair;
    for (int j = t; j < npair; j += HTHREADS) dst[j] = h[j];
}

// 1b) fold the NHB private histograms into cnt (coalesced reads, no atomics)
__global__ __launch_bounds__(256) void sumhist_kernel(const unsigned int* __restrict__ bhist,
                                                      int* __restrict__ cnt,
                                                      int npair, int M) {
    int i = blockIdx.x * 256 + threadIdx.x;
    if (i >= npair) return;
    int lo = 0, hi = 0;
    for (int b = 0; b < NHB; ++b) {
        unsigned int v = bhist[(size_t)b * npair + i];
        lo += (int)(v & 0xFFFFu);
        hi += (int)(v >> 16);
    }
    if (2 * i < M)     cnt[2 * i]     = lo;
    if (2 * i + 1 < M) cnt[2 * i + 1] = hi;
}

// 2) FUSED single-kernel exclusive scan
__global__ __launch_bounds__(256) void scan_kernel(const int* __restrict__ cnt,
                                                   int* __restrict__ off,
                                                   int* __restrict__ cursor, int n) {
    __shared__ int sh[SCAN_ITEMS];
    __shared__ int ts[256];
    __shared__ int pre[256];
    const int b = blockIdx.x, t = threadIdx.x;
    const int base = b * SCAN_ITEMS;

    int p = 0;
    for (int i = t; i < base; i += 256) p += cnt[i];
    pre[t] = p;
    __syncthreads();
    for (int st = 128; st > 0; st >>= 1) {
        if (t < st) pre[t] += pre[t + st];
        __syncthreads();
    }
    const int block_base = pre[0];
    __syncthreads();

    #pragma unroll
    for (int j = 0; j < 8; ++j) {
        int i = base + j * 256 + t;
        sh[j * 256 + t] = (i < n) ? cnt[i] : 0;
    }
    __syncthreads();
    int s = 0;
    #pragma unroll
    for (int j = 0; j < 8; ++j) s += sh[t * 8 + j];
    ts[t] = s;
    __syncthreads();
    for (int st = 1; st < 256; st <<= 1) {
        int u = (t >= st) ? ts[t - st] : 0;
        __syncthreads();
        ts[t] += u;
        __syncthreads();
    }
    int run = block_base + ts[t] - s;
    #pragma unroll
    for (int j = 0; j < 8; ++j) {
        int i = base + t * 8 + j;
        if (i < n) {
            off[i] = run;
            cursor[i] = run;
            run += sh[t * 8 + j];
        }
    }
}

// 3) scatter edge ids into segment-sorted order (int4 loads)
__global__ __launch_bounds__(256) void order_kernel(const int* __restrict__ index,
                                                    int* __restrict__ cursor,
                                                    int* __restrict__ order, int n4, int n) {
    int i = blockIdx.x * 256 + threadIdx.x;
    if (i < n4) {
        int4 v = reinterpret_cast<const int4*>(index)[i];
        int e = 4 * i;
        order[atomicAdd(&cursor[v.x], 1)] = e;
        order[atomicAdd(&cursor[v.y], 1)] = e + 1;
        order[atomicAdd(&cursor[v.z], 1)] = e + 2;
        order[atomicAdd(&cursor[v.w], 1)] = e + 3;
    }
    int rem = 4 * n4 + i;
    if (i < n - 4 * n4) order[atomicAdd(&cursor[index[rem]], 1)] = rem;
}

// 4) one wave per segment (round-9 body, byte-identical math), wrapped in
//    REP_R idempotent reps (DIAGNOSTIC — recomputes and rewrites same values).
__global__ __launch_bounds__(256) void reduce_kernel(
    const float* __restrict__ src, const int* __restrict__ order,
    const int* __restrict__ off, unsigned short* __restrict__ A_b, int nseg)
{
    int wid  = (blockIdx.x * 256 + threadIdx.x) >> 6;
    int lane = threadIdx.x & 63;
    if (wid >= nseg) return;
    const int half = lane >> 5;
    const int fl   = (lane & 31) << 2;

    const int start = off[wid], end = off[wid + 1];

    for (int rep = 0; rep < REP_R; ++rep) {
        f32x4 s = {0.f, 0.f, 0.f, 0.f};
        f32x4 m = {-INFINITY, -INFINITY, -INFINITY, -INFINITY};

        for (int base = start; base < end; base += 64) {
            int idx = base + lane;
            int eo  = (idx < end) ? order[idx] : 0;
            int lim = end - base; if (lim > 64) lim = 64;
            #pragma unroll 2
            for (int j = 0; j < lim; j += 2) {
                int jj = j + half;
                int e  = __shfl(eo, jj);
                if (jj < lim) {
                    f32x4 v = *reinterpret_cast<const f32x4*>(src + (size_t)e * D_FEAT + fl);
                    s.x += v.x; s.y += v.y; s.z += v.z; s.w += v.w;
                    m.x = fmaxf(m.x, v.x); m.y = fmaxf(m.y, v.y);
                    m.z = fmaxf(m.z, v.z); m.w = fmaxf(m.w, v.w);
                }
            }
        }

        s.x += __shfl_xor(s.x, 32); s.y += __shfl_xor(s.y, 32);
        s.z += __shfl_xor(s.z, 32); s.w += __shfl_xor(s.w, 32);
        m.x = fmaxf(m.x, __shfl_xor(m.x, 32)); m.y = fmaxf(m.y, __shfl_xor(m.y, 32));
        m.z = fmaxf(m.z, __shfl_xor(m.z, 32)); m.w = fmaxf(m.w, __shfl_xor(m.w, 32));

        if (end == start) { m.x = 0.f; m.y = 0.f; m.z = 0.f; m.w = 0.f; }

        const f32x4 o = (half == 0) ? s : m;
        unsigned int lo = (unsigned int)f2bf(o.x) | ((unsigned int)f2bf(o.y) << 16);
        unsigned int hi = (unsigned int)f2bf(o.z) | ((unsigned int)f2bf(o.w) << 16);
        unsigned short* row = A_b + (size_t)wid * (2 * D_FEAT) + half * D_FEAT;
        uint2 pk = make_uint2(lo, hi);
        *reinterpret_cast<uint2*>(row + fl) = pk;

        asm volatile("" ::: "memory");   // keep both reps live (rule #17)
    }
}

// 5) MFMA GEMM: out[M,128] = A_b[M,256](bf16) @ W^T + bias, fp32 accum.
__global__ __launch_bounds__(256) void gemm_mfma_kernel(
    const unsigned short* __restrict__ A_b, const unsigned short* __restrict__ Wfrag,
    const float* __restrict__ bias, float* __restrict__ out, int M)
{
    const int w  = threadIdx.x >> 6;
    const int l  = threadIdx.x & 63;
    const int m0 = blockIdx.x * 64 + w * 16;
    if (m0 >= M) return;

    const int arow = m0 + (l & 15);
    const int kgrp = (l >> 4) << 3;

    f32x4 acc[8];
    #pragma unroll
    for (int c = 0; c < 8; ++c) acc[c] = (f32x4){0.f, 0.f, 0.f, 0.f};

    #pragma unroll
    for (int s = 0; s < 8; ++s) {
        short8 a = *reinterpret_cast<const short8*>(A_b + (size_t)arow * 256 + s * 32 + kgrp);
        #pragma unroll
        for (int c = 0; c < 8; ++c) {
            short8 b = *reinterpret_cast<const short8*>(Wfrag + (((size_t)(c * 8 + s)) * 64 + l) * 8);
            acc[c] = __builtin_amdgcn_mfma_f32_16x16x32_bf16(a, b, acc[c], 0, 0, 0);
        }
    }

    const int r0   = m0 + ((l >> 4) << 2);
    const int colb = l & 15;
    #pragma unroll
    for (int c = 0; c < 8; ++c) {
        int col = c * 16 + colb;
        float bv = bias[col];
        #pragma unroll
        for (int r = 0; r < 4; ++r) {
            int rw = r0 + r;
            if (rw < M) out[(size_t)rw * D_FEAT + col] = acc[c][r] + bv;
        }
    }
}

extern "C" void kernel_launch(void* const* d_in, const int* in_sizes, int n_in,
                              void* d_out, int out_size, void* d_ws, size_t ws_size,
                              hipStream_t stream) {
    const float* src   = (const float*)d_in[0];
    const int*   index = (const int*)d_in[1];
    const float* W     = (const float*)d_in[2];
    const float* bias  = (const float*)d_in[3];

    const int n_edges = in_sizes[1];            // 1,600,000
    const int M       = out_size / D_FEAT;      // 50,000
    const int Mpad    = (M + 63) & ~63;
    const int npair   = (M + 1) >> 1;           // 25,000 (<= MAXPAIR)

    // workspace layout
    unsigned short* A_b   = (unsigned short*)d_ws;            // Mpad * 256 bf16
    unsigned short* Wfrag = A_b + (size_t)Mpad * 2 * D_FEAT;  // 32768 bf16
    int*   cnt    = (int*)(Wfrag + 2 * D_FEAT * D_FEAT);      // M
    int*   off    = cnt + M;                                  // M + 1
    int*   cursor = off + M + 1;                              // M
    int*   order  = cursor + M;                               // n_edges
    unsigned int* bhist = (unsigned int*)(order + n_edges);   // NHB * npair

    const int nblk = (M + SCAN_ITEMS - 1) / SCAN_ITEMS;       // 25

    int n4 = n_edges / 4;
    hist_kernel<<<NHB, HTHREADS, 0, stream>>>(index, bhist, W, Wfrag, off,
                                              M, npair, n4, n_edges);
    sumhist_kernel<<<(npair + 255) / 256, 256, 0, stream>>>(bhist, cnt, npair, M);

    scan_kernel<<<nblk, 256, 0, stream>>>(cnt, off, cursor, M);

    int eb4 = (max(n4, n_edges - 4 * n4) + 255) / 256;
    order_kernel<<<eb4, 256, 0, stream>>>(index, cursor, order, n4, n_edges);

    int rb = (M * 64 + 255) / 256;
    reduce_kernel<<<rb, 256, 0, stream>>>(src, order, off, A_b, M);

    gemm_mfma_kernel<<<(M + 63) / 64, 256, 0, stream>>>(A_b, Wfrag, bias, (float*)d_out, M);
}

// Round 14
// 367.361 us; speedup vs baseline: 1.0866x; 1.0477x over previous
//
#include <hip/hip_runtime.h>
#include <math.h>

#define D_FEAT 128
#define SCAN_ITEMS 2048   // items per scan block (256 thr * 8)
#define NHB 256           // hist blocks (private LDS histograms)
#define HTHREADS 1024     // hist block size
#define MAXPAIR 25600     // max (M+1)/2 supported by static LDS (100 KB)

typedef float f32x4 __attribute__((ext_vector_type(4)));
typedef short short8 __attribute__((ext_vector_type(8)));

// float -> bf16 (RNE), on raw bits
__device__ __forceinline__ unsigned short f2bf(float f) {
    unsigned int u = __float_as_uint(f);
    u += 0x7FFFu + ((u >> 16) & 1u);
    return (unsigned short)(u >> 16);
}

// 1) LDS-privatized histogram. Block NHB-1 also builds fragment-major bf16 W
//    and off[M] (folded setup).
__global__ __launch_bounds__(HTHREADS) void hist_kernel(const int* __restrict__ index,
                                                        unsigned int* __restrict__ bhist,
                                                        const float* __restrict__ W,
                                                        unsigned short* __restrict__ Wfrag,
                                                        int* __restrict__ off,
                                                        int M, int npair, int n4, int n) {
    __shared__ unsigned int h[MAXPAIR];
    const int b = blockIdx.x, t = threadIdx.x;

    if (b == NHB - 1) {
        for (int i = t; i < 2 * D_FEAT * D_FEAT; i += HTHREADS) {
            int ii = i & 7, lf = (i >> 3) & 63, sf = (i >> 9) & 7, cf = i >> 12;
            int col = cf * 16 + (lf & 15);
            int k   = sf * 32 + ((lf >> 4) << 3) + ii;
            Wfrag[i] = f2bf(W[(size_t)col * (2 * D_FEAT) + k]);
        }
        if (t == 0) off[M] = n;
    }

    for (int j = t; j < npair; j += HTHREADS) h[j] = 0u;
    __syncthreads();

    const int per = (n4 + NHB - 1) / NHB;
    const int i0 = b * per;
    const int i1 = min(n4, i0 + per);
    const int4* idx4 = reinterpret_cast<const int4*>(index);
    for (int i = i0 + t; i < i1; i += HTHREADS) {
        int4 v = idx4[i];
        atomicAdd(&h[v.x >> 1], 1u << ((v.x & 1) << 4));
        atomicAdd(&h[v.y >> 1], 1u << ((v.y & 1) << 4));
        atomicAdd(&h[v.z >> 1], 1u << ((v.z & 1) << 4));
        atomicAdd(&h[v.w >> 1], 1u << ((v.w & 1) << 4));
    }
    if (b == 0) {
        for (int r = 4 * n4 + t; r < n; r += HTHREADS) {
            int v = index[r];
            atomicAdd(&h[v >> 1], 1u << ((v & 1) << 4));
        }
    }
    __syncthreads();

    unsigned int* dst = bhist + (size_t)b * npair;
    for (int j = t; j < npair; j += HTHREADS) dst[j] = h[j];
}

// 1b) fold the NHB private histograms into cnt
__global__ __launch_bounds__(256) void sumhist_kernel(const unsigned int* __restrict__ bhist,
                                                      int* __restrict__ cnt,
                                                      int npair, int M) {
    int i = blockIdx.x * 256 + threadIdx.x;
    if (i >= npair) return;
    int lo = 0, hi = 0;
    for (int b = 0; b < NHB; ++b) {
        unsigned int v = bhist[(size_t)b * npair + i];
        lo += (int)(v & 0xFFFFu);
        hi += (int)(v >> 16);
    }
    if (2 * i < M)     cnt[2 * i]     = lo;
    if (2 * i + 1 < M) cnt[2 * i + 1] = hi;
}

// 2) FUSED single-kernel exclusive scan
__global__ __launch_bounds__(256) void scan_kernel(const int* __restrict__ cnt,
                                                   int* __restrict__ off,
                                                   int* __restrict__ cursor, int n) {
    __shared__ int sh[SCAN_ITEMS];
    __shared__ int ts[256];
    __shared__ int pre[256];
    const int b = blockIdx.x, t = threadIdx.x;
    const int base = b * SCAN_ITEMS;

    int p = 0;
    for (int i = t; i < base; i += 256) p += cnt[i];
    pre[t] = p;
    __syncthreads();
    for (int st = 128; st > 0; st >>= 1) {
        if (t < st) pre[t] += pre[t + st];
        __syncthreads();
    }
    const int block_base = pre[0];
    __syncthreads();

    #pragma unroll
    for (int j = 0; j < 8; ++j) {
        int i = base + j * 256 + t;
        sh[j * 256 + t] = (i < n) ? cnt[i] : 0;
    }
    __syncthreads();
    int s = 0;
    #pragma unroll
    for (int j = 0; j < 8; ++j) s += sh[t * 8 + j];
    ts[t] = s;
    __syncthreads();
    for (int st = 1; st < 256; st <<= 1) {
        int u = (t >= st) ? ts[t - st] : 0;
        __syncthreads();
        ts[t] += u;
        __syncthreads();
    }
    int run = block_base + ts[t] - s;
    #pragma unroll
    for (int j = 0; j < 8; ++j) {
        int i = base + t * 8 + j;
        if (i < n) {
            off[i] = run;
            cursor[i] = run;
            run += sh[t * 8 + j];
        }
    }
}

// 3) scatter edge ids into segment-sorted order
__global__ __launch_bounds__(256) void order_kernel(const int* __restrict__ index,
                                                    int* __restrict__ cursor,
                                                    int* __restrict__ order, int n4, int n) {
    int i = blockIdx.x * 256 + threadIdx.x;
    if (i < n4) {
        int4 v = reinterpret_cast<const int4*>(index)[i];
        int e = 4 * i;
        order[atomicAdd(&cursor[v.x], 1)] = e;
        order[atomicAdd(&cursor[v.y], 1)] = e + 1;
        order[atomicAdd(&cursor[v.z], 1)] = e + 2;
        order[atomicAdd(&cursor[v.w], 1)] = e + 3;
    }
    int rem = 4 * n4 + i;
    if (i < n - 4 * n4) order[atomicAdd(&cursor[index[rem]], 1)] = rem;
}

// 4) FUSED reduce+GEMM. Block = 16 consecutive segments (M % 16 == 0).
//    Phase 1: wave w reduces segments seg0+4w..+3 (whole wave per segment;
//    dual accumulator sets -> 4 rows in flight) into a 16x(256+pad) bf16 LDS
//    tile (row = sum[0:128] | max[128:256], verified A-frag layout source).
//    Phase 2: wave w MFMAs cols [32w, 32w+32) for all 16 rows and stores out.
__global__ __launch_bounds__(256) void redgemm_kernel(
    const float* __restrict__ src, const int* __restrict__ order,
    const int* __restrict__ off, const unsigned short* __restrict__ Wfrag,
    const float* __restrict__ bias, float* __restrict__ out, int M)
{
    __shared__ __align__(16) unsigned short atile[16][264];   // +8 pad: 2-way banks

    const int w    = threadIdx.x >> 6;
    const int lane = threadIdx.x & 63;
    const int half = lane >> 5;
    const int fl   = (lane & 31) << 2;
    const int seg0 = blockIdx.x * 16;

    // ---- phase 1: reduction ----
    for (int q = 0; q < 4; ++q) {
        const int seg = seg0 + w * 4 + q;
        const int r   = w * 4 + q;
        if (seg < M) {
            const int start = off[seg], end = off[seg + 1];

            f32x4 s0 = {0.f,0.f,0.f,0.f}, s1 = {0.f,0.f,0.f,0.f};
            f32x4 m0 = {-INFINITY,-INFINITY,-INFINITY,-INFINITY}, m1 = m0;

            for (int base = start; base < end; base += 64) {
                int idx = base + lane;
                int eo  = (idx < end) ? order[idx] : 0;
                int lim = end - base; if (lim > 64) lim = 64;
                for (int j = 0; j < lim; j += 4) {      // uniform trips
                    int jj0 = j + half;                 // <= 61
                    int jj1 = j + 2 + half;             // <= 63
                    int e0 = __shfl(eo, jj0);
                    int e1 = __shfl(eo, jj1);
                    if (jj0 < lim) {
                        f32x4 v = *reinterpret_cast<const f32x4*>(src + (size_t)e0 * D_FEAT + fl);
                        s0.x += v.x; s0.y += v.y; s0.z += v.z; s0.w += v.w;
                        m0.x = fmaxf(m0.x, v.x); m0.y = fmaxf(m0.y, v.y);
                        m0.z = fmaxf(m0.z, v.z); m0.w = fmaxf(m0.w, v.w);
                    }
                    if (jj1 < lim) {
                        f32x4 v = *reinterpret_cast<const f32x4*>(src + (size_t)e1 * D_FEAT + fl);
                        s1.x += v.x; s1.y += v.y; s1.z += v.z; s1.w += v.w;
                        m1.x = fmaxf(m1.x, v.x); m1.y = fmaxf(m1.y, v.y);
                        m1.z = fmaxf(m1.z, v.z); m1.w = fmaxf(m1.w, v.w);
                    }
                }
            }

            f32x4 s = {s0.x + s1.x, s0.y + s1.y, s0.z + s1.z, s0.w + s1.w};
            f32x4 m = {fmaxf(m0.x, m1.x), fmaxf(m0.y, m1.y),
                       fmaxf(m0.z, m1.z), fmaxf(m0.w, m1.w)};

            s.x += __shfl_xor(s.x, 32); s.y += __shfl_xor(s.y, 32);
            s.z += __shfl_xor(s.z, 32); s.w += __shfl_xor(s.w, 32);
            m.x = fmaxf(m.x, __shfl_xor(m.x, 32)); m.y = fmaxf(m.y, __shfl_xor(m.y, 32));
            m.z = fmaxf(m.z, __shfl_xor(m.z, 32)); m.w = fmaxf(m.w, __shfl_xor(m.w, 32));

            if (end == start) { m.x = 0.f; m.y = 0.f; m.z = 0.f; m.w = 0.f; }

            const f32x4 o = (half == 0) ? s : m;
            unsigned int lo = (unsigned int)f2bf(o.x) | ((unsigned int)f2bf(o.y) << 16);
            unsigned int hi = (unsigned int)f2bf(o.z) | ((unsigned int)f2bf(o.w) << 16);
            *reinterpret_cast<uint2*>(&atile[r][fl + half * D_FEAT]) = make_uint2(lo, hi);
        } else {
            *reinterpret_cast<uint2*>(&atile[r][fl + half * D_FEAT]) = make_uint2(0u, 0u);
        }
    }
    __syncthreads();

    // ---- phase 2: MFMA epilogue (verified fragment mappings from gemm_mfma) ----
    f32x4 acc0 = {0.f,0.f,0.f,0.f}, acc1 = {0.f,0.f,0.f,0.f};
    const int arow = lane & 15;
    const int kgrp = (lane >> 4) << 3;
    #pragma unroll
    for (int s = 0; s < 8; ++s) {
        short8 a = *reinterpret_cast<const short8*>(&atile[arow][s * 32 + kgrp]);
        short8 b0 = *reinterpret_cast<const short8*>(Wfrag + (((size_t)((2*w  ) * 8 + s)) * 64 + lane) * 8);
        short8 b1 = *reinterpret_cast<const short8*>(Wfrag + (((size_t)((2*w+1) * 8 + s)) * 64 + lane) * 8);
        acc0 = __builtin_amdgcn_mfma_f32_16x16x32_bf16(a, b0, acc0, 0, 0, 0);
        acc1 = __builtin_amdgcn_mfma_f32_16x16x32_bf16(a, b1, acc1, 0, 0, 0);
    }

    const int r0   = (lane >> 4) << 2;
    const int colb = lane & 15;
    #pragma unroll
    for (int cc = 0; cc < 2; ++cc) {
        const f32x4 acc = cc ? acc1 : acc0;
        int col = (2 * w + cc) * 16 + colb;
        float bv = bias[col];
        #pragma unroll
        for (int r = 0; r < 4; ++r) {
            int row = seg0 + r0 + r;
            if (row < M) out[(size_t)row * D_FEAT + col] = acc[r] + bv;
        }
    }
}

extern "C" void kernel_launch(void* const* d_in, const int* in_sizes, int n_in,
                              void* d_out, int out_size, void* d_ws, size_t ws_size,
                              hipStream_t stream) {
    const float* src   = (const float*)d_in[0];
    const int*   index = (const int*)d_in[1];
    const float* W     = (const float*)d_in[2];
    const float* bias  = (const float*)d_in[3];

    const int n_edges = in_sizes[1];            // 1,600,000
    const int M       = out_size / D_FEAT;      // 50,000 (divisible by 16)
    const int npair   = (M + 1) >> 1;           // 25,000 (<= MAXPAIR)

    // workspace layout
    unsigned short* Wfrag = (unsigned short*)d_ws;            // 32768 bf16 (64KB)
    int*   cnt    = (int*)(Wfrag + 2 * D_FEAT * D_FEAT);      // M
    int*   off    = cnt + M;                                  // M + 1
    int*   cursor = off + M + 1;                              // M
    int*   order  = cursor + M;                               // n_edges
    unsigned int* bhist = (unsigned int*)(order + n_edges);   // NHB * npair

    const int nblk = (M + SCAN_ITEMS - 1) / SCAN_ITEMS;       // 25

    int n4 = n_edges / 4;
    hist_kernel<<<NHB, HTHREADS, 0, stream>>>(index, bhist, W, Wfrag, off,
                                              M, npair, n4, n_edges);
    sumhist_kernel<<<(npair + 255) / 256, 256, 0, stream>>>(bhist, cnt, npair, M);

    scan_kernel<<<nblk, 256, 0, stream>>>(cnt, off, cursor, M);

    int eb4 = (max(n4, n_edges - 4 * n4) + 255) / 256;
    order_kernel<<<eb4, 256, 0, stream>>>(index, cursor, order, n4, n_edges);

    redgemm_kernel<<<(M + 15) / 16, 256, 0, stream>>>(src, order, off, Wfrag, bias,
                                                      (float*)d_out, M);
}